// Round 6
// baseline (63.103 us; speedup 1.0000x reference)
//
#include <hip/hip_runtime.h>
#include <hip/hip_bf16.h>
#include <stdint.h>

#define HH 128
#define WW 128
#define HWPX 16384
#define BIGL 16384           // background sentinel
#define NT 1024
#define PPT 16               // contiguous pixels per thread (one 16-col row chunk)

// bank swizzle: logical index -> physical LDS slot (involution, bijective).
__device__ __forceinline__ int SW(int i) { return i ^ ((i >> 5) & 31); }

// find during merge: READ-ONLY chase + one plain-store tail compression.
// Safety: values at L[x] only decrease; once L[x]!=x is observed, no union can
// ever succeed AT x again (that needs L[b]==b), so racing writes here are all
// redundant ancestor-shortcuts — any ancestor value is valid, LWW is fine.
__device__ __forceinline__ int findRootH(int* L, int x) {
    int p = L[SW(x)];
    if (p == x) return x;
    int r = p, q = L[SW(r)];
    while (q != r) { r = q; q = L[SW(r)]; }
    if (p != r) L[SW(x)] = r;      // tail compression at diverse address
    return r;
}
// post-merge find with plain-store halving (no concurrent unions)
__device__ __forceinline__ int findRootF(int* L, int x) {
    int p = L[SW(x)];
    while (p != x) {
        int g = L[SW(p)];
        if (g != p) L[SW(x)] = g;
        x = p; p = g;
    }
    return p;
}
// lock-free union by min index (atomicMin only on believed-root entries)
__device__ __forceinline__ void uni(int* L, int a, int b) {
    a = findRootH(L, a);
    b = findRootH(L, b);
    while (a != b) {
        if (a > b) { int t = a; a = b; b = t; }
        int old = atomicMin(&L[SW(b)], a);
        if (old == b) break;
        b = findRootH(L, old);
    }
}

__device__ __forceinline__ int wsumi(int v)    { for (int o = 32; o; o >>= 1) v += __shfl_xor(v, o, 64); return v; }
__device__ __forceinline__ float wsumf(float v){ for (int o = 32; o; o >>= 1) v += __shfl_xor(v, o, 64); return v; }
__device__ __forceinline__ int wmini(int v)    { for (int o = 32; o; o >>= 1) v = min(v, __shfl_xor(v, o, 64)); return v; }
__device__ __forceinline__ int wmaxi(int v)    { for (int o = 32; o; o >>= 1) v = max(v, __shfl_xor(v, o, 64)); return v; }

__global__ __launch_bounds__(NT)
void cc_kernel(const float* __restrict__ masks, float* __restrict__ losses) {
    __shared__ int L[HWPX];              // 64 KB: UF parent (swizzled); roots get area<<16
    __shared__ unsigned rowbits[HH][4];  // 2 KB: fg bitmap
    __shared__ int s_bg;
    __shared__ int s_r0, s_r1, s_c0, s_c1;
    __shared__ unsigned s_k2;
    __shared__ unsigned s_wk[32];
    __shared__ float s_wsum[16];
    __shared__ float s_total;

    const int tid = threadIdx.x;
    const int lane = tid & 63;
    const int wid = tid >> 6;
    const float* msk = masks + (size_t)blockIdx.x * HWPX;
    const int base = tid * PPT;
    const int row  = base >> 7;
    const int col0 = base & 127;

    // ---- vectorized load, fg detect, total sum, run-head label init ----
    float vals[PPT];
    const float4* m4 = (const float4*)(msk + base);
#pragma unroll
    for (int q = 0; q < 4; ++q) {
        float4 v = m4[q];
        vals[q * 4 + 0] = v.x; vals[q * 4 + 1] = v.y;
        vals[q * 4 + 2] = v.z; vals[q * 4 + 3] = v.w;
    }
    unsigned fgbits = 0;
    float tsum = 0.f;
    {
        int start = -1;
#pragma unroll
        for (int k = 0; k < PPT; ++k) {
            tsum += vals[k];
            int i = base + k;
            if (vals[k] > 0.f) {
                fgbits |= 1u << k;
                if (start < 0) start = k;
                L[SW(i)] = base + start;
            } else {
                start = -1;
                L[SW(i)] = BIGL;
            }
        }
    }
    unsigned lf = __shfl(fgbits, lane > 0 ? lane - 1 : lane, 64);
    unsigned rf = __shfl(fgbits, lane < 63 ? lane + 1 : lane, 64);
    const unsigned leftbit  = (col0 > 0)   ? ((lf >> 15) & 1u) : 0u;
    const unsigned rightbit = (col0 < 112) ? (rf & 1u)         : 0u;
    unsigned other = __shfl_xor(fgbits, 1, 64);
    if (!(tid & 1)) rowbits[row][(tid >> 1) & 3] = fgbits | (other << 16);

    tsum = wsumf(tsum);
    if (lane == 0) s_wsum[wid] = tsum;
    if (tid == 0) { s_bg = 0; s_r0 = HH; s_r1 = -1; s_c0 = WW; s_c1 = -1; }
    __syncthreads();

    // ---- wave0: total; all: merge pass (dedup'd unions) ----
    if (tid < 64) {
        float t = (tid < 16) ? s_wsum[tid] : 0.f;
        for (int o = 8; o; o >>= 1) t += __shfl_xor(t, o, 64);
        if (tid == 0) s_total = t;
    }
    if (fgbits) {
        unsigned up = 0;
        if (row > 0) {
            const int wi  = col0 >> 5;
            const int off = col0 & 31;
            unsigned w0 = rowbits[row - 1][wi];
            unsigned w1 = (wi < 3) ? rowbits[row - 1][wi + 1] : 0u;
            unsigned long long uv = ((unsigned long long)w1 << 32) | w0;
            if (off == 16) {
                up = (unsigned)(uv >> 15) & 0x3FFFFu;
            } else {
                unsigned lw = (col0 > 0) ? rowbits[row - 1][wi - 1] : 0u;
                up = (unsigned)((uv << 1) | (lw >> 31)) & 0x3FFFFu;
            }
        }
        if ((fgbits & 1u) && leftbit) uni(L, base, base - 1);
        unsigned m = fgbits;
        while (m) {
            int k = __ffs(m) - 1; m &= m - 1;
            int i = base + k;
            unsigned UL = (up >> k) & 1u;
            unsigned UP = (up >> (k + 1)) & 1u;
            unsigned UR = (up >> (k + 2)) & 1u;
            unsigned lF = k ? ((fgbits >> (k - 1)) & 1u) : leftbit;
            unsigned rF = (k < 15) ? ((fgbits >> (k + 1)) & 1u) : rightbit;
            if (!lF) {
                if (UL)        uni(L, i, i - WW - 1);
                if (UP && !UL) uni(L, i, i - WW);
                if (UR && !UP) uni(L, i, i - WW + 1);
            } else {
                if (UP && !UL)        uni(L, i, i - WW);
                if (!rF && UR && !UP) uni(L, i, i - WW + 1);
            }
        }
    }
    __syncthreads();

    // ---- flatten: one find per run; compress run heads; track first root ----
    int rr[PPT];
    int firstRoot = 0x7FFFFFFF;
    {
        int cur = -1;
#pragma unroll
        for (int k = 0; k < PPT; ++k) {
            rr[k] = -1;
            if (fgbits & (1u << k)) {
                if (k == 0 || !(fgbits & (1u << (k - 1)))) {
                    cur = findRootF(L, base + k);
                    L[SW(base + k)] = cur;
                }
                rr[k] = cur;
                if (firstRoot == 0x7FFFFFFF) firstRoot = cur;
            }
        }
    }
    __syncthreads();

    // ---- areas: wave-combined for dominant root, run-length for the rest ----
    {
        const int R0 = wmini(firstRoot);          // wave-uniform hot root
        int giant = 0, bgc = 0, prev = -1, cnt = 0;
#pragma unroll
        for (int k = 0; k < PPT; ++k) {
            if (!(fgbits & (1u << k))) { ++bgc; continue; }
            int r = rr[k];
            if (r == R0) { ++giant; }
            else if (r == prev) ++cnt;
            else {
                if (cnt) atomicAdd(&L[SW(prev)], cnt << 16);
                prev = r; cnt = 1;
            }
        }
        if (cnt) atomicAdd(&L[SW(prev)], cnt << 16);
        int g = wsumi(giant);
        if (lane == 0 && R0 != 0x7FFFFFFF && g) atomicAdd(&L[SW(R0)], g << 16);
        int b = wsumi(bgc);
        if (lane == 0 && b) atomicAdd(&s_bg, b);
    }
    __syncthreads();

    // ---- top-2 by key = (area<<15) | (BIGL - label) ----
    int bg = s_bg;
    unsigned b1 = 0, b2 = 0;
    if (tid == 0 && bg > 0) b1 = ((unsigned)bg << 15);
    for (int i = tid; i < HWPX; i += NT) {
        int e = L[SW(i)];
        if ((e & 0xFFFF) == i && (e >> 16) != 0) {
            unsigned key = ((unsigned)(e >> 16) << 15) | (unsigned)(BIGL - i);
            if (key > b1) { b2 = b1; b1 = key; }
            else if (key > b2) b2 = key;
        }
    }
    for (int o = 32; o; o >>= 1) {
        unsigned p1 = __shfl_xor(b1, o, 64);
        unsigned p2 = __shfl_xor(b2, o, 64);
        if (p1 > b1) { b2 = (b1 > p2 ? b1 : p2); b1 = p1; }
        else if (p1 > b2) b2 = p1;
    }
    if (lane == 0) { s_wk[wid * 2] = b1; s_wk[wid * 2 + 1] = b2; }
    __syncthreads();
    if (tid < 64) {
        unsigned o1 = (tid < 16) ? s_wk[tid * 2] : 0u;
        unsigned o2 = (tid < 16) ? s_wk[tid * 2 + 1] : 0u;
        for (int o = 8; o; o >>= 1) {
            unsigned p1 = __shfl_xor(o1, o, 64);
            unsigned p2 = __shfl_xor(o2, o, 64);
            if (p1 > o1) { o2 = (o1 > p2 ? o1 : p2); o1 = p1; }
            else if (p1 > o2) o2 = p1;
        }
        if (tid == 0) s_k2 = o2;
    }
    __syncthreads();

    unsigned k2 = s_k2;
    bool have2 = (k2 >> 15) != 0;
    int j = BIGL - (int)(k2 & 0x7FFFu);      // runner-up label (BIGL == background)

    // ---- bbox of component j (wave-combined atomics) ----
    if (have2) {
        int lc0 = WW, lc1 = -1;
#pragma unroll
        for (int k = 0; k < PPT; ++k) {
            bool inc = (fgbits & (1u << k)) ? (rr[k] == j) : (j == BIGL);
            if (inc) {
                int c = col0 + k;
                lc0 = min(lc0, c); lc1 = max(lc1, c);
            }
        }
        int lr0 = (lc1 >= 0) ? row : HH;
        int lr1 = (lc1 >= 0) ? row : -1;
        lr0 = wmini(lr0); lr1 = wmaxi(lr1);
        lc0 = wmini(lc0); lc1 = wmaxi(lc1);
        if (lane == 0 && lr1 >= 0) {
            atomicMin(&s_r0, lr0); atomicMax(&s_r1, lr1);
            atomicMin(&s_c0, lc0); atomicMax(&s_c1, lc1);
        }
    }
    __syncthreads();

    // ---- sum inside box (from registers) ----
    float bsum = 0.f;
    if (have2) {
        int r0 = s_r0, r1 = s_r1, c0 = s_c0, c1 = s_c1;
        if (row >= r0 && row <= r1) {
#pragma unroll
            for (int k = 0; k < PPT; ++k) {
                int c = col0 + k;
                if (c >= c0 && c <= c1) bsum += vals[k];
            }
        }
    }
    bsum = wsumf(bsum);
    __syncthreads();
    if (lane == 0) s_wsum[wid] = bsum;
    __syncthreads();
    if (tid < 64) {
        float t = (tid < 16) ? s_wsum[tid] : 0.f;
        for (int o = 8; o; o >>= 1) t += __shfl_xor(t, o, 64);
        if (tid == 0) losses[blockIdx.x] = (s_total - t) * (1.0f / 16384.0f);
    }
}

__global__ void reduce_kernel(const float* __restrict__ losses, float* __restrict__ out, int n) {
    __shared__ float s[4];
    int t = threadIdx.x;                      // 256 threads
    float v = 0.f;
    for (int i = t; i < n; i += 256) v += losses[i];
    for (int off = 32; off; off >>= 1) v += __shfl_down(v, off, 64);
    if ((t & 63) == 0) s[t >> 6] = v;
    __syncthreads();
    if (t == 0) out[0] = (s[0] + s[1] + s[2] + s[3]) / (float)n;
}

extern "C" void kernel_launch(void* const* d_in, const int* in_sizes, int n_in,
                              void* d_out, int out_size, void* d_ws, size_t ws_size,
                              hipStream_t stream) {
    const float* masks = (const float*)d_in[0];
    float* out = (float*)d_out;
    float* losses = (float*)d_ws;
    int nmask = in_sizes[0] / HWPX;          // 8*16 = 128
    cc_kernel<<<nmask, NT, 0, stream>>>(masks, losses);
    reduce_kernel<<<1, 256, 0, stream>>>(losses, out, nmask);
}

// Round 7
// 48.078 us; speedup vs baseline: 1.3125x; 1.3125x over previous
//
#include <hip/hip_runtime.h>
#include <hip/hip_bf16.h>
#include <stdint.h>

#define HH 128
#define WW 128
#define HWPX 16384
#define BIGL 16384           // background sentinel
#define NT 1024
#define PPT 16               // contiguous pixels per thread (one 16-col row chunk)

// find with path-halving via atomicMin (monotone decrease -> always acyclic,
// safe under concurrent unions; R4-validated, fastest variant measured)
__device__ __forceinline__ int findRootH(int* L, int x) {
    int p = L[x];
    while (p != x) {
        int g = L[p];
        if (g != p) atomicMin(&L[x], g);   // halving: g is ancestor, g < p
        x = p; p = g;
    }
    return x;
}
// post-merge find with plain-store halving (no concurrent unions)
__device__ __forceinline__ int findRootF(int* L, int x) {
    int p = L[x];
    while (p != x) {
        int g = L[p];
        if (g != p) L[x] = g;
        x = p; p = g;
    }
    return p;
}
// lock-free union by min index
__device__ __forceinline__ void uni(int* L, int a, int b) {
    a = findRootH(L, a);
    b = findRootH(L, b);
    while (a != b) {
        if (a > b) { int t = a; a = b; b = t; }
        int old = atomicMin(&L[b], a);
        if (old == b) break;
        b = findRootH(L, old);
    }
}

__device__ __forceinline__ int wsumi(int v)    { for (int o = 32; o; o >>= 1) v += __shfl_xor(v, o, 64); return v; }
__device__ __forceinline__ float wsumf(float v){ for (int o = 32; o; o >>= 1) v += __shfl_xor(v, o, 64); return v; }
__device__ __forceinline__ int wmini(int v)    { for (int o = 32; o; o >>= 1) v = min(v, __shfl_xor(v, o, 64)); return v; }
__device__ __forceinline__ int wmaxi(int v)    { for (int o = 32; o; o >>= 1) v = max(v, __shfl_xor(v, o, 64)); return v; }

__global__ __launch_bounds__(NT)
void cc_kernel(const float* __restrict__ masks, float* __restrict__ losses) {
    __shared__ int L[HWPX];              // 64 KB: UF parent; roots get area<<16
    __shared__ unsigned rowbits[HH][4];  // 2 KB: fg bitmap
    __shared__ int s_bg;
    __shared__ int s_r0, s_r1, s_c0, s_c1;
    __shared__ unsigned s_k2;
    __shared__ unsigned s_wk[32];
    __shared__ float s_wsum[16];
    __shared__ float s_total;

    const int tid = threadIdx.x;
    const int lane = tid & 63;
    const int wid = tid >> 6;
    const float* msk = masks + (size_t)blockIdx.x * HWPX;
    const int base = tid * PPT;
    const int row  = base >> 7;
    const int col0 = base & 127;

    // ---- vectorized load, fg detect, total sum, run-head labels in regs ----
    float vals[PPT];
    const float4* m4 = (const float4*)(msk + base);
#pragma unroll
    for (int q = 0; q < 4; ++q) {
        float4 v = m4[q];
        vals[q * 4 + 0] = v.x; vals[q * 4 + 1] = v.y;
        vals[q * 4 + 2] = v.z; vals[q * 4 + 3] = v.w;
    }
    unsigned fgbits = 0;
    float tsum = 0.f;
    int lab[PPT];
    {
        int start = -1;
#pragma unroll
        for (int k = 0; k < PPT; ++k) {
            tsum += vals[k];
            if (vals[k] > 0.f) {
                fgbits |= 1u << k;
                if (start < 0) start = k;
                lab[k] = base + start;
            } else {
                start = -1;
                lab[k] = BIGL;
            }
        }
    }
    // vectorized label init: 4x ds_write_b128
    {
        int4* Lv = (int4*)(L + base);
#pragma unroll
        for (int q = 0; q < 4; ++q)
            Lv[q] = make_int4(lab[q * 4], lab[q * 4 + 1], lab[q * 4 + 2], lab[q * 4 + 3]);
    }
    unsigned lf = __shfl(fgbits, lane > 0 ? lane - 1 : lane, 64);
    unsigned rf = __shfl(fgbits, lane < 63 ? lane + 1 : lane, 64);
    const unsigned leftbit  = (col0 > 0)   ? ((lf >> 15) & 1u) : 0u;
    const unsigned rightbit = (col0 < 112) ? (rf & 1u)         : 0u;
    unsigned other = __shfl_xor(fgbits, 1, 64);
    if (!(tid & 1)) rowbits[row][(tid >> 1) & 3] = fgbits | (other << 16);

    tsum = wsumf(tsum);
    if (lane == 0) s_wsum[wid] = tsum;
    if (tid == 0) { s_bg = 0; s_r0 = HH; s_r1 = -1; s_c0 = WW; s_c1 = -1; }
    __syncthreads();

    // ---- wave0: total; all: merge pass (event-masked dedup'd unions) ----
    if (tid < 64) {
        float t = (tid < 16) ? s_wsum[tid] : 0.f;
        for (int o = 8; o; o >>= 1) t += __shfl_xor(t, o, 64);
        if (tid == 0) s_total = t;
    }
    if (fgbits) {
        unsigned up = 0;
        if (row > 0) {
            const int wi  = col0 >> 5;
            const int off = col0 & 31;
            unsigned w0 = rowbits[row - 1][wi];
            unsigned w1 = (wi < 3) ? rowbits[row - 1][wi + 1] : 0u;
            unsigned long long uv = ((unsigned long long)w1 << 32) | w0;
            if (off == 16) {
                up = (unsigned)(uv >> 15) & 0x3FFFFu;
            } else {
                unsigned lw = (col0 > 0) ? rowbits[row - 1][wi - 1] : 0u;
                up = (unsigned)((uv << 1) | (lw >> 31)) & 0x3FFFFu;
            }
        }
        if ((fgbits & 1u) && leftbit) uni(L, base, base - 1);
        // per-pixel neighbor vectors (bit k = that flag for pixel k)
        const unsigned ULv = up & 0xFFFFu;
        const unsigned UPv = (up >> 1) & 0xFFFFu;
        const unsigned URv = (up >> 2) & 0xFFFFu;
        const unsigned lFv = ((fgbits << 1) | leftbit) & 0xFFFFu;
        const unsigned rFv = (fgbits >> 1) | (rightbit << 15);
        // pixels that issue at least one union
        unsigned m = fgbits & ( (~lFv & (ULv | UPv | URv))
                              | (lFv & ((UPv & ~ULv) | (~rFv & URv & ~UPv))) );
        while (m) {
            int k = __ffs(m) - 1; m &= m - 1;
            int i = base + k;
            unsigned UL = (ULv >> k) & 1u;
            unsigned UP = (UPv >> k) & 1u;
            unsigned UR = (URv >> k) & 1u;
            unsigned lF = (lFv >> k) & 1u;
            unsigned rF = (rFv >> k) & 1u;
            if (!lF) {
                if (UL)        uni(L, i, i - WW - 1);
                if (UP && !UL) uni(L, i, i - WW);
                if (UR && !UP) uni(L, i, i - WW + 1);
            } else {
                if (UP && !UL)        uni(L, i, i - WW);
                if (!rF && UR && !UP) uni(L, i, i - WW + 1);
            }
        }
    }
    __syncthreads();

    // ---- flatten: one find per run; compress run heads; track first root ----
    int rr[PPT];
    int firstRoot = 0x7FFFFFFF;
    {
        int cur = -1;
#pragma unroll
        for (int k = 0; k < PPT; ++k) {
            rr[k] = -1;
            if (fgbits & (1u << k)) {
                if (k == 0 || !(fgbits & (1u << (k - 1)))) {
                    cur = findRootF(L, base + k);
                    L[base + k] = cur;
                }
                rr[k] = cur;
                if (firstRoot == 0x7FFFFFFF) firstRoot = cur;
            }
        }
    }
    __syncthreads();

    // ---- areas: wave-combined for dominant root, run-length for the rest ----
    {
        const int R0 = wmini(firstRoot);          // wave-uniform hot root
        int giant = 0, bgc = 0, prev = -1, cnt = 0;
#pragma unroll
        for (int k = 0; k < PPT; ++k) {
            if (!(fgbits & (1u << k))) { ++bgc; continue; }
            int r = rr[k];
            if (r == R0) { ++giant; }
            else if (r == prev) ++cnt;
            else {
                if (cnt) atomicAdd(&L[prev], cnt << 16);
                prev = r; cnt = 1;
            }
        }
        if (cnt) atomicAdd(&L[prev], cnt << 16);
        int g = wsumi(giant);
        if (lane == 0 && R0 != 0x7FFFFFFF && g) atomicAdd(&L[R0], g << 16);
        int b = wsumi(bgc);
        if (lane == 0 && b) atomicAdd(&s_bg, b);
    }
    __syncthreads();

    // ---- top-2 by key = (area<<15) | (BIGL - label), scan run heads only ----
    // (a component's root is always a chunk-local run head: its left neighbor
    //  can't be fg, else that neighbor would have a smaller flat index)
    int bg = s_bg;
    unsigned b1 = 0, b2 = 0;
    if (tid == 0 && bg > 0) b1 = ((unsigned)bg << 15);
    {
        unsigned m = fgbits & ~(fgbits << 1);     // chunk-local run heads
        while (m) {
            int k = __ffs(m) - 1; m &= m - 1;
            int h = base + k;
            int e = L[h];
            if ((e & 0xFFFF) == h && (e >> 16) != 0) {
                unsigned key = ((unsigned)(e >> 16) << 15) | (unsigned)(BIGL - h);
                if (key > b1) { b2 = b1; b1 = key; }
                else if (key > b2) b2 = key;
            }
        }
    }
    for (int o = 32; o; o >>= 1) {
        unsigned p1 = __shfl_xor(b1, o, 64);
        unsigned p2 = __shfl_xor(b2, o, 64);
        if (p1 > b1) { b2 = (b1 > p2 ? b1 : p2); b1 = p1; }
        else if (p1 > b2) b2 = p1;
    }
    if (lane == 0) { s_wk[wid * 2] = b1; s_wk[wid * 2 + 1] = b2; }
    __syncthreads();
    if (tid < 64) {
        unsigned o1 = (tid < 16) ? s_wk[tid * 2] : 0u;
        unsigned o2 = (tid < 16) ? s_wk[tid * 2 + 1] : 0u;
        for (int o = 8; o; o >>= 1) {
            unsigned p1 = __shfl_xor(o1, o, 64);
            unsigned p2 = __shfl_xor(o2, o, 64);
            if (p1 > o1) { o2 = (o1 > p2 ? o1 : p2); o1 = p1; }
            else if (p1 > o2) o2 = p1;
        }
        if (tid == 0) s_k2 = o2;
    }
    __syncthreads();

    unsigned k2 = s_k2;
    bool have2 = (k2 >> 15) != 0;
    int j = BIGL - (int)(k2 & 0x7FFFu);      // runner-up label (BIGL == background)

    // ---- bbox of component j (wave-combined atomics) ----
    if (have2) {
        int lc0 = WW, lc1 = -1;
#pragma unroll
        for (int k = 0; k < PPT; ++k) {
            bool inc = (fgbits & (1u << k)) ? (rr[k] == j) : (j == BIGL);
            if (inc) {
                int c = col0 + k;
                lc0 = min(lc0, c); lc1 = max(lc1, c);
            }
        }
        int lr0 = (lc1 >= 0) ? row : HH;
        int lr1 = (lc1 >= 0) ? row : -1;
        lr0 = wmini(lr0); lr1 = wmaxi(lr1);
        lc0 = wmini(lc0); lc1 = wmaxi(lc1);
        if (lane == 0 && lr1 >= 0) {
            atomicMin(&s_r0, lr0); atomicMax(&s_r1, lr1);
            atomicMin(&s_c0, lc0); atomicMax(&s_c1, lc1);
        }
    }
    __syncthreads();

    // ---- sum inside box (from registers) ----
    float bsum = 0.f;
    if (have2) {
        int r0 = s_r0, r1 = s_r1, c0 = s_c0, c1 = s_c1;
        if (row >= r0 && row <= r1) {
#pragma unroll
            for (int k = 0; k < PPT; ++k) {
                int c = col0 + k;
                if (c >= c0 && c <= c1) bsum += vals[k];
            }
        }
    }
    bsum = wsumf(bsum);
    __syncthreads();
    if (lane == 0) s_wsum[wid] = bsum;
    __syncthreads();
    if (tid < 64) {
        float t = (tid < 16) ? s_wsum[tid] : 0.f;
        for (int o = 8; o; o >>= 1) t += __shfl_xor(t, o, 64);
        if (tid == 0) losses[blockIdx.x] = (s_total - t) * (1.0f / 16384.0f);
    }
}

__global__ void reduce_kernel(const float* __restrict__ losses, float* __restrict__ out, int n) {
    __shared__ float s[4];
    int t = threadIdx.x;                      // 256 threads
    float v = 0.f;
    for (int i = t; i < n; i += 256) v += losses[i];
    for (int off = 32; off; off >>= 1) v += __shfl_down(v, off, 64);
    if ((t & 63) == 0) s[t >> 6] = v;
    __syncthreads();
    if (t == 0) out[0] = (s[0] + s[1] + s[2] + s[3]) / (float)n;
}

extern "C" void kernel_launch(void* const* d_in, const int* in_sizes, int n_in,
                              void* d_out, int out_size, void* d_ws, size_t ws_size,
                              hipStream_t stream) {
    const float* masks = (const float*)d_in[0];
    float* out = (float*)d_out;
    float* losses = (float*)d_ws;
    int nmask = in_sizes[0] / HWPX;          // 8*16 = 128
    cc_kernel<<<nmask, NT, 0, stream>>>(masks, losses);
    reduce_kernel<<<1, 256, 0, stream>>>(losses, out, nmask);
}